// Round 1
// 674.104 us; speedup vs baseline: 1.0058x; 1.0058x over previous
//
#include <hip/hip_runtime.h>
#include <hip/hip_bf16.h>
#include <math.h>

// Problem shape: B=1024, N=256, D=512, fp32.
// out = log(pos + neg) - log(pos)
//   pos = sum_b exp(dot(normalize(img[b]), fg_pro[b]))
//   neg = sum_{b,n} exp(dot(normalize(img[b]), bg_pro[b][n]))
// bg_pro = 512 MiB streamed once -> ~86 us kernel floor at 6.3 TB/s.
//
// R4: explicit 2-deep software pipeline in the stream phase. The previous
// version relied on the compiler to schedule 32 independent float4 loads
// from a fully-unrolled loop; depending on its VGPR/vmcnt choices that can
// either collapse occupancy (hoist-all) or serialize (drain-all before each
// dot group). Here we ping-pong two 8xfloat4 staging register sets so ~16
// loads are always in flight per wave while the previous group's FMAs run.
// Everything else (NSPLIT=4 decomposition, reduction order, finalize) is
// unchanged from the passing R3 kernel.

#define D_DIM   512
#define NSPLIT  4                 // blocks per batch row
#define ROWS_PER_WAVE 16          // N / NSPLIT / 4 waves = 256/4/4

__global__ __launch_bounds__(256) void infonce_main(
    const float* __restrict__ img,     // [B, D]
    const float* __restrict__ fg_pro,  // [B, D]
    const float* __restrict__ bg_pro,  // [B, N, D]
    float* __restrict__ accum,         // accum[0]=pos_sum, accum[1]=neg_sum
    int N)
{
    const int b     = blockIdx.x >> 2;        // NSPLIT == 4
    const int split = blockIdx.x & 3;
    const int tid   = threadIdx.x;            // 0..255
    const int wid   = tid >> 6;               // wave 0..3
    const int lane  = tid & 63;

    __shared__ float s_img[D_DIM];            // normalized image row
    __shared__ float s_red[8];

    // ---- 1. load img[b], sum of squares (2 floats/thread) ----
    const float2 v = reinterpret_cast<const float2*>(img + (size_t)b * D_DIM)[tid];
    float ss = v.x * v.x + v.y * v.y;
    #pragma unroll
    for (int off = 32; off > 0; off >>= 1) ss += __shfl_xor(ss, off);
    if (lane == 0) s_red[wid] = ss;
    __syncthreads();
    const float inv = rsqrtf(s_red[0] + s_red[1] + s_red[2] + s_red[3]);

    // ---- 2. normalized row -> LDS; pos dot (split 0 only) ----
    const float2 nv = make_float2(v.x * inv, v.y * inv);
    reinterpret_cast<float2*>(s_img)[tid] = nv;

    if (split == 0) {
        const float2 p = reinterpret_cast<const float2*>(fg_pro + (size_t)b * D_DIM)[tid];
        float pd = nv.x * p.x + nv.y * p.y;
        #pragma unroll
        for (int off = 32; off > 0; off >>= 1) pd += __shfl_xor(pd, off);
        if (lane == 0) s_red[4 + wid] = pd;
    }
    __syncthreads();                          // covers s_img + s_red[4..7]
    if (split == 0 && tid == 0) {
        const float pos = s_red[4] + s_red[5] + s_red[6] + s_red[7];
        atomicAdd(&accum[0], expf(pos));
    }

    // ---- 3. phase 1: pure stream, explicit 2-deep pipeline ----
    const int n0 = split * (N / NSPLIT) + wid * ROWS_PER_WAVE;

    const float4* s_img4 = reinterpret_cast<const float4*>(s_img);
    const float4  a0 = s_img4[lane];          // d = 4*lane
    const float4  a1 = s_img4[64 + lane];     // d = 256 + 4*lane

    const float4* bg4 = reinterpret_cast<const float4*>(
        bg_pro + (size_t)b * N * D_DIM + (size_t)n0 * D_DIM);

    float part[ROWS_PER_WAVE];                // per-lane partial dot per row

    // Group g covers rows 4g..4g+3; row stride = D_DIM/4 = 128 float4s.
    // Per group: 8 coalesced float4 loads (1 KiB/lane-group each, 8 KiB
    // contiguous per wave-group).
#define LOADG(g, B0,B1,B2,B3,B4,B5,B6,B7) do {                        \
        const float4* r_ = bg4 + (size_t)(g) * (4 * (D_DIM / 4));      \
        B0 = r_[      lane]; B1 = r_[ 64 + lane];                      \
        B2 = r_[128 + lane]; B3 = r_[192 + lane];                      \
        B4 = r_[256 + lane]; B5 = r_[320 + lane];                      \
        B6 = r_[384 + lane]; B7 = r_[448 + lane];                      \
    } while (0)

#define DOTR(dst, BA, BB)                                              \
        dst = a0.x*BA.x + a0.y*BA.y + a0.z*BA.z + a0.w*BA.w            \
            + a1.x*BB.x + a1.y*BB.y + a1.z*BB.z + a1.w*BB.w

#define DOTG(i, B0,B1,B2,B3,B4,B5,B6,B7) do {                          \
        DOTR(part[(i)+0], B0, B1);                                     \
        DOTR(part[(i)+1], B2, B3);                                     \
        DOTR(part[(i)+2], B4, B5);                                     \
        DOTR(part[(i)+3], B6, B7);                                     \
    } while (0)

    float4 x0, x1, x2, x3, x4, x5, x6, x7;    // staging set A
    float4 y0, y1, y2, y3, y4, y5, y6, y7;    // staging set B

    LOADG(0, x0, x1, x2, x3, x4, x5, x6, x7);           // fill pipe
    LOADG(1, y0, y1, y2, y3, y4, y5, y6, y7);           // 16 loads in flight
    DOTG (0, x0, x1, x2, x3, x4, x5, x6, x7);           // consume g0 (waits x only)
    LOADG(2, x0, x1, x2, x3, x4, x5, x6, x7);           // refill A
    DOTG (4, y0, y1, y2, y3, y4, y5, y6, y7);           // consume g1
    LOADG(3, y0, y1, y2, y3, y4, y5, y6, y7);           // refill B
    DOTG (8, x0, x1, x2, x3, x4, x5, x6, x7);           // consume g2
    DOTG (12, y0, y1, y2, y3, y4, y5, y6, y7);          // consume g3 (drain)

#undef LOADG
#undef DOTR
#undef DOTG

    // ---- 4. phase 2: tail reduce (butterflies + expf, off the load path) ----
    float local = 0.0f;
    #pragma unroll
    for (int i = 0; i < ROWS_PER_WAVE; i += 4) {
        float d0 = part[i + 0], d1 = part[i + 1],
              d2 = part[i + 2], d3 = part[i + 3];
        #pragma unroll
        for (int off = 32; off > 0; off >>= 1) {
            d0 += __shfl_xor(d0, off);
            d1 += __shfl_xor(d1, off);
            d2 += __shfl_xor(d2, off);
            d3 += __shfl_xor(d3, off);
        }
        if (lane == 0)
            local += expf(d0) + expf(d1) + expf(d2) + expf(d3);
    }

    if (lane == 0) s_red[wid] = local;
    __syncthreads();
    if (tid == 0)
        atomicAdd(&accum[1], s_red[0] + s_red[1] + s_red[2] + s_red[3]);
}

__global__ void infonce_finalize(const float* __restrict__ accum,
                                 float* __restrict__ out)
{
    const float pos = accum[0];
    const float neg = accum[1];
    out[0] = logf(pos + neg) - logf(pos);   // == -log(pos/(pos+neg))
}

extern "C" void kernel_launch(void* const* d_in, const int* in_sizes, int n_in,
                              void* d_out, int out_size, void* d_ws, size_t ws_size,
                              hipStream_t stream)
{
    const float* img = (const float*)d_in[0];   // [B, D]
    const float* fg  = (const float*)d_in[1];   // [B, D]
    const float* bg  = (const float*)d_in[2];   // [B, N, D]
    float* out   = (float*)d_out;
    float* accum = (float*)d_ws;                // 2 floats

    const int B = in_sizes[0] / D_DIM;
    const int N = in_sizes[2] / in_sizes[0];

    hipMemsetAsync(accum, 0, 2 * sizeof(float), stream);
    infonce_main<<<B * NSPLIT, 256, 0, stream>>>(img, fg, bg, accum, N);
    infonce_finalize<<<1, 1, 0, stream>>>(accum, out);
}

// Round 2
// 600.008 us; speedup vs baseline: 1.1300x; 1.1235x over previous
//
#include <hip/hip_runtime.h>
#include <hip/hip_bf16.h>
#include <math.h>

// Problem shape: B=1024, N=256, D=512, fp32.
// out = log(pos + neg) - log(pos)
//   pos = sum_b exp(dot(normalize(img[b]), fg_pro[b]))
//   neg = sum_{b,n} exp(dot(normalize(img[b]), bg_pro[b][n]))
// bg_pro = 512 MiB streamed once -> ~86 us kernel floor at 6.3 TB/s.
//
// R5: occupancy + dispatch-count experiment (discriminates "main is slow"
// vs "harness overhead floor").
//  - NSPLIT 4 -> 16: 16384 blocks, 4 rows/wave, only 8 float4 staged per
//    lane (~64-80 VGPRs vs ~190) -> 3-4x more resident waves/CU.
//  - No hipMemsetAsync, no atomics: each block writes a partial sum into
//    the workspace (poisoned values are fully overwritten before finalize
//    reads them); finalize reduces 17408 floats in one block.
//  - __launch_bounds__(256,4) pins VGPRs <= 128 (>= 16 waves/CU).

#define D_DIM   512
#define NSPLIT  16                // blocks per batch row
#define ROWS_PER_WAVE 4           // (N / NSPLIT) / 4 waves = 16/4

__global__ __launch_bounds__(256, 4) void infonce_main(
    const float* __restrict__ img,     // [B, D]
    const float* __restrict__ fg_pro,  // [B, D]
    const float* __restrict__ bg_pro,  // [B, N, D]
    float* __restrict__ part_out,      // [B*NSPLIT] neg partials, then [B] pos
    int N, int B)
{
    const int bid   = blockIdx.x;
    const int b     = bid >> 4;               // NSPLIT == 16
    const int split = bid & 15;
    const int tid   = threadIdx.x;            // 0..255
    const int wid   = tid >> 6;               // wave 0..3
    const int lane  = tid & 63;

    __shared__ float s_img[D_DIM];            // normalized image row
    __shared__ float s_red[8];

    // ---- 1. load img[b], sum of squares (2 floats/thread) ----
    const float2 v = reinterpret_cast<const float2*>(img + (size_t)b * D_DIM)[tid];
    float ss = v.x * v.x + v.y * v.y;
    #pragma unroll
    for (int off = 32; off > 0; off >>= 1) ss += __shfl_xor(ss, off);
    if (lane == 0) s_red[wid] = ss;
    __syncthreads();
    const float inv = rsqrtf(s_red[0] + s_red[1] + s_red[2] + s_red[3]);

    // ---- 2. normalized row -> LDS; pos dot (split 0 only) ----
    const float2 nv = make_float2(v.x * inv, v.y * inv);
    reinterpret_cast<float2*>(s_img)[tid] = nv;

    if (split == 0) {
        const float2 p = reinterpret_cast<const float2*>(fg_pro + (size_t)b * D_DIM)[tid];
        float pd = nv.x * p.x + nv.y * p.y;
        #pragma unroll
        for (int off = 32; off > 0; off >>= 1) pd += __shfl_xor(pd, off);
        if (lane == 0) s_red[4 + wid] = pd;
    }
    __syncthreads();                          // covers s_img + s_red[4..7]
    if (split == 0 && tid == 0) {
        const float pos = s_red[4] + s_red[5] + s_red[6] + s_red[7];
        part_out[(size_t)B * NSPLIT + b] = expf(pos);   // no atomic, no init
    }

    // ---- 3. stream 4 rows/wave: 8 float4 loads in flight per lane ----
    const int n0 = split * (N / NSPLIT) + wid * ROWS_PER_WAVE;

    const float4* s_img4 = reinterpret_cast<const float4*>(s_img);
    const float4  a0 = s_img4[lane];          // d = 4*lane
    const float4  a1 = s_img4[64 + lane];     // d = 256 + 4*lane

    const float4* bg4 = reinterpret_cast<const float4*>(
        bg_pro + (size_t)b * N * D_DIM + (size_t)n0 * D_DIM);

    const float4* r0 = bg4;
    const float4* r1 = bg4 + 1 * (D_DIM / 4);
    const float4* r2 = bg4 + 2 * (D_DIM / 4);
    const float4* r3 = bg4 + 3 * (D_DIM / 4);
    const float4 b00 = r0[lane], b01 = r0[64 + lane];
    const float4 b10 = r1[lane], b11 = r1[64 + lane];
    const float4 b20 = r2[lane], b21 = r2[64 + lane];
    const float4 b30 = r3[lane], b31 = r3[64 + lane];

    float d0 = a0.x*b00.x + a0.y*b00.y + a0.z*b00.z + a0.w*b00.w
             + a1.x*b01.x + a1.y*b01.y + a1.z*b01.z + a1.w*b01.w;
    float d1 = a0.x*b10.x + a0.y*b10.y + a0.z*b10.z + a0.w*b10.w
             + a1.x*b11.x + a1.y*b11.y + a1.z*b11.z + a1.w*b11.w;
    float d2 = a0.x*b20.x + a0.y*b20.y + a0.z*b20.z + a0.w*b20.w
             + a1.x*b21.x + a1.y*b21.y + a1.z*b21.z + a1.w*b21.w;
    float d3 = a0.x*b30.x + a0.y*b30.y + a0.z*b30.z + a0.w*b30.w
             + a1.x*b31.x + a1.y*b31.y + a1.z*b31.z + a1.w*b31.w;

    // ---- 4. tail reduce: butterflies + expf ----
    #pragma unroll
    for (int off = 32; off > 0; off >>= 1) {
        d0 += __shfl_xor(d0, off);
        d1 += __shfl_xor(d1, off);
        d2 += __shfl_xor(d2, off);
        d3 += __shfl_xor(d3, off);
    }
    if (lane == 0)
        s_red[wid] = expf(d0) + expf(d1) + expf(d2) + expf(d3);
    __syncthreads();
    if (tid == 0)
        part_out[bid] = s_red[0] + s_red[1] + s_red[2] + s_red[3];
}

__global__ __launch_bounds__(256) void infonce_finalize(
    const float* __restrict__ part, float* __restrict__ out,
    int nneg, int npos)
{
    const int tid = threadIdx.x;
    float neg = 0.0f, pos = 0.0f;
    for (int i = tid; i < nneg; i += 256) neg += part[i];
    for (int i = tid; i < npos; i += 256) pos += part[nneg + i];
    #pragma unroll
    for (int off = 32; off > 0; off >>= 1) {
        neg += __shfl_xor(neg, off);
        pos += __shfl_xor(pos, off);
    }
    __shared__ float sn[4], sp[4];
    if ((tid & 63) == 0) { sn[tid >> 6] = neg; sp[tid >> 6] = pos; }
    __syncthreads();
    if (tid == 0) {
        const float P = sp[0] + sp[1] + sp[2] + sp[3];
        const float Ntot = sn[0] + sn[1] + sn[2] + sn[3];
        out[0] = logf(P + Ntot) - logf(P);   // == -log(pos/(pos+neg))
    }
}

extern "C" void kernel_launch(void* const* d_in, const int* in_sizes, int n_in,
                              void* d_out, int out_size, void* d_ws, size_t ws_size,
                              hipStream_t stream)
{
    const float* img = (const float*)d_in[0];   // [B, D]
    const float* fg  = (const float*)d_in[1];   // [B, D]
    const float* bg  = (const float*)d_in[2];   // [B, N, D]
    float* out  = (float*)d_out;
    float* part = (float*)d_ws;                 // [B*NSPLIT + B] floats

    const int B = in_sizes[0] / (D_DIM * (int)sizeof(float));
    const int N = in_sizes[2] / in_sizes[0];

    infonce_main<<<B * NSPLIT, 256, 0, stream>>>(img, fg, bg, part, N, B);
    infonce_finalize<<<1, 256, 0, stream>>>(part, out, B * NSPLIT, B);
}